// Round 18
// baseline (154.404 us; speedup 1.0000x reference)
//
#include <hip/hip_runtime.h>
#include <hip/hip_bf16.h>
#include <stdint.h>

#define HD 64
#define NH 16
#define TT 2048
#define DD 1024

typedef uint16_t u16;
typedef __bf16 bf16_t;
typedef bf16_t bf16x8 __attribute__((ext_vector_type(8)));
typedef float f32x4 __attribute__((ext_vector_type(4)));

__device__ __forceinline__ u16 f2b(float f) {
    union { float f; uint32_t u; } v; v.f = f;
    uint32_t u = v.u;
    u += 0x7fff + ((u >> 16) & 1);   // RNE
    return (u16)(u >> 16);
}

__device__ __forceinline__ u16 b16(float f) {
    union { __bf16 h; u16 u; } c; c.h = (__bf16)f; return c.u;  // HW cvt (RNE)
}

// native v_exp_f32: D = 2^S0 (single instruction; exp2f libm is ~10 VALU ops)
__device__ __forceinline__ float ex2(float x) { return __builtin_amdgcn_exp2f(x); }

__device__ __forceinline__ void gload16(const void* g, void* l) {
    __builtin_amdgcn_global_load_lds(
        (__attribute__((address_space(1))) void*)g,
        (__attribute__((address_space(3))) void*)l, 16, 0, 0);
}

// ---------------- converts ----------------

__global__ void f32_to_bf16_vec(const float* __restrict__ in, u16* __restrict__ out, int n4) {
    int i = blockIdx.x * 256 + threadIdx.x;
    if (i >= n4) return;
    float4 v = ((const float4*)in)[i];
    ushort4 r;
    r.x = f2b(v.x); r.y = f2b(v.y); r.z = f2b(v.z); r.w = f2b(v.w);
    ((ushort4*)out)[i] = r;
}

// out[c][r] = bf16(in[r][c]); R,C multiples of 32; block (32,8)
__global__ void transpose_f32_bf16(const float* __restrict__ in, u16* __restrict__ out, int R, int C) {
    __shared__ float tile[32][33];
    const int tx = threadIdx.x, ty = threadIdx.y;
    const int c0 = blockIdx.x * 32, r0 = blockIdx.y * 32;
#pragma unroll
    for (int j = 0; j < 32; j += 8)
        tile[ty + j][tx] = in[(size_t)(r0 + ty + j) * C + c0 + tx];
    __syncthreads();
#pragma unroll
    for (int j = 0; j < 32; j += 8)
        out[(size_t)(c0 + ty + j) * R + r0 + tx] = f2b(tile[tx][ty + j]);
}

// ---------------- GEMM C = A[M,K] * Bt[N,K]^T, bf16 in, f32 acc ----------------
// gemm10: BM=128 x BN=128, BK=64, 512 thr (8 waves 4Mx2N, 32x64/wave).
// 2-slot LDS = 64 KB -> 2 blocks/CU. 16 sync chains: per K-tile {vmcnt(0) of
// loads issued a full iteration ago -> ONE barrier -> STG(t+1) -> 12 ds_read ->
// 16 MFMA}. chunk^(row&7) swizzle via pre-swizzled global src.
// XCD swizzle, B-REUSE ORDER (r18): each XCD owns row panels [8k,8k+8); within
// an XCD, 8 consecutive blocks share ONE B col-panel (256 KB, L2-resident) and
// walk the 8 A row-panels (XCD A slice 2 MB, L2-resident) -> both operands
// L2-hit in steady state (r17: col-fast order thrashed B 8x through L2, FETCH 84MB).
// Grids EXACT: MODE0 1536 = 3.0 rounds, MODE1 512 = 1.0 round; both have
// exactly 8 row panels per XCD (M=8192 -> 64 = 8 XCDs x 8).
// MODE 0: scatter epilogue -> q (x log2e/8), k, vT.  MODE 1: f32 store.

template<int MODE>
__global__ __launch_bounds__(512, 4)
void gemm10(const u16* __restrict__ A, const u16* __restrict__ Bt,
            int N, int K, int nwg,
            u16* __restrict__ oq, u16* __restrict__ ok, u16* __restrict__ ovT,
            float* __restrict__ of)
{
    __shared__ __align__(16) u16 As[2][128 * 64];   // 32 KiB
    __shared__ __align__(16) u16 Bs[2][128 * 64];   // 32 KiB
    const int tid = threadIdx.x;
    const int lane = tid & 63, l15 = lane & 15, g = lane >> 4;
    const int wid = tid >> 6, wm = wid >> 1, wn = wid & 1;

    // XCD-aware, B-reuse-ordered swizzle: rows fast within a col panel
    const int xcd = blockIdx.x & 7, j = blockIdx.x >> 3;
    const long row0 = (long)(xcd * 8 + (j & 7)) * 128;
    const long col0 = (long)(j >> 3) * 128;

    const u16* Ag = A + row0 * K;
    const u16* Bg = Bt + col0 * K;

    const f32x4 z4 = {0.f, 0.f, 0.f, 0.f};
    f32x4 acc[2][4];
#pragma unroll
    for (int i = 0; i < 2; i++)
#pragma unroll
        for (int n = 0; n < 4; n++) acc[i][n] = z4;

    const int sw = l15 & 7;   // read-side chunk XOR (row&7)

#define STG(t_, s_) do { const int ko = (t_) << 6;                                                  \
        { const int c = tid;       const int r_ = c >> 3;                                           \
          gload16(Ag + (size_t)r_ * K + ko + (((c & 7) ^ (r_ & 7)) << 3), &As[s_][c << 3]); }       \
        { const int c = tid + 512; const int r_ = c >> 3;                                           \
          gload16(Ag + (size_t)r_ * K + ko + (((c & 7) ^ (r_ & 7)) << 3), &As[s_][c << 3]); }       \
        { const int c = tid;       const int r_ = c >> 3;                                           \
          gload16(Bg + (size_t)r_ * K + ko + (((c & 7) ^ (r_ & 7)) << 3), &Bs[s_][c << 3]); }       \
        { const int c = tid + 512; const int r_ = c >> 3;                                           \
          gload16(Bg + (size_t)r_ * K + ko + (((c & 7) ^ (r_ & 7)) << 3), &Bs[s_][c << 3]); }       \
    } while (0)

    const int NT = K >> 6;   // 16
    STG(0, 0);
    for (int t = 0; t < NT; ++t) {
        const int cur = t & 1;
        asm volatile("s_waitcnt vmcnt(0)" ::: "memory");   // tile t's 4 loads (issued 1 iter ago)
        __builtin_amdgcn_s_barrier();                       // slot cur^1 now free
        if (t + 1 < NT) STG(t + 1, cur ^ 1);
#pragma unroll
        for (int ks = 0; ks < 2; ks++) {
            bf16x8 af[2], bfr[4];
            const int ce = ((ks * 4 + g) ^ sw) << 3;        // swizzled chunk offset (u16 units)
#pragma unroll
            for (int m = 0; m < 2; m++)
                af[m]  = *(const bf16x8*)&As[cur][(wm * 32 + m * 16 + l15) * 64 + ce];
#pragma unroll
            for (int n = 0; n < 4; n++)
                bfr[n] = *(const bf16x8*)&Bs[cur][(wn * 64 + n * 16 + l15) * 64 + ce];
            __builtin_amdgcn_s_setprio(1);
#pragma unroll
            for (int m = 0; m < 2; m++)
#pragma unroll
                for (int n = 0; n < 4; n++)
                    acc[m][n] = __builtin_amdgcn_mfma_f32_16x16x32_bf16(af[m], bfr[n], acc[m][n], 0, 0, 0);
            __builtin_amdgcn_s_setprio(0);
        }
    }
#undef STG

    if (MODE == 0) {
        const int which = (int)(col0 >> 10);
        const long b = row0 >> 11;
#pragma unroll
        for (int m = 0; m < 2; m++) {
            const long r = row0 + wm * 32 + m * 16 + g * 4;
            const long t = r & (TT - 1);
#pragma unroll
            for (int n = 0; n < 4; n++) {
                const long c = col0 + wn * 64 + n * 16 + l15;
                const int h  = (int)((c >> 6) & 15);
                const int hd = (int)(c & 63);
                if (which == 0) {
                    // q scaled by (1/8) * log2(e): softmax runs in exp2 domain
#pragma unroll
                    for (int e = 0; e < 4; e++)
                        oq[((b * NH + h) * TT + t + e) * HD + hd] = f2b(acc[m][n][e] * 0.18033688f);
                } else if (which == 1) {
#pragma unroll
                    for (int e = 0; e < 4; e++)
                        ok[((b * NH + h) * TT + t + e) * HD + hd] = f2b(acc[m][n][e]);
                } else {
                    ushort4 pk;
                    pk.x = f2b(acc[m][n][0]); pk.y = f2b(acc[m][n][1]);
                    pk.z = f2b(acc[m][n][2]); pk.w = f2b(acc[m][n][3]);
                    *(ushort4*)&ovT[((b * NH + h) * HD + hd) * TT + t] = pk;
                }
            }
        }
    } else {
#pragma unroll
        for (int m = 0; m < 2; m++) {
            const long r = row0 + wm * 32 + m * 16 + g * 4;
#pragma unroll
            for (int n = 0; n < 4; n++) {
                const long c = col0 + wn * 64 + n * 16 + l15;
#pragma unroll
                for (int e = 0; e < 4; e++)
                    of[(r + e) * (long)N + c] = acc[m][n][e];
            }
        }
    }
}

// ---------------- flash attention (r17-exact: MFMA row-sum) ----------------
// 1D grid 1024: blockIdx.x -> (qt heavy-first, bh). 256 threads (4 waves x 32 q).
// KV tiles of 64 keys, double-buffered (2-slot), counted vmcnt(4), raw s_barrier x2.
// K/V LDS XOR-swizzled (chunk ^ row&7, via pre-swizzled global src).
// QK^T SWAPPED: s = mfma(K,Q) -> q = lane&15, key = g*4+e (in-lane row).
// In-register online softmax, exp2 domain (v_exp_f32).
// ls computed as P x ones via one extra MFMA per (ks,qi) in o_acc's C/D layout.
// P repacked through per-wave LDS as 8B granules, granule ^ l15 swizzle.

__global__ __launch_bounds__(256, 3)
void attn_fwd(const u16* __restrict__ gq, const u16* __restrict__ gk,
              const u16* __restrict__ gvT, u16* __restrict__ o)
{
    __shared__ __align__(16) u16 Klds[2][64 * 64];   // [key][hd] swizzled
    __shared__ __align__(16) u16 Vlds[2][64 * 64];   // [hd][key] swizzled
    __shared__ __align__(16) u16 Plds[4][32 * 64];   // per-wave [q][16 x 8B granules]

    const int tid = threadIdx.x;
    const int wv = tid >> 6, lane = tid & 63, l15 = lane & 15, g = lane >> 4;
    const int bh = blockIdx.x & 63;
    const int qt = 15 - (blockIdx.x >> 6);       // heavy tiles dispatch first
    const int q0 = qt * 128;
    const int qw0 = q0 + wv * 32;

    const u16* qbase = gq + (size_t)bh * TT * HD;
    const u16* kbase = gk + (size_t)bh * TT * HD;
    const u16* vbase = gvT + (size_t)bh * HD * TT;

    const float NEG_INF = -__builtin_inff();
    const f32x4 z4 = {0.f, 0.f, 0.f, 0.f};
    const bf16x8 ones = {(__bf16)1.f, (__bf16)1.f, (__bf16)1.f, (__bf16)1.f,
                         (__bf16)1.f, (__bf16)1.f, (__bf16)1.f, (__bf16)1.f};

    bf16x8 qf[2][2];
#pragma unroll
    for (int qi = 0; qi < 2; qi++)
#pragma unroll
        for (int hs = 0; hs < 2; hs++)
            qf[qi][hs] = *(const bf16x8*)(qbase + (size_t)(qw0 + qi * 16 + l15) * HD + hs * 32 + g * 8);

    f32x4 o_acc[2][4];
    f32x4 ls_acc[2];            // row-sum of P, in o_acc's C/D layout (row q = g*4+e)
    float m[2];
#pragma unroll
    for (int qi = 0; qi < 2; qi++) {
#pragma unroll
        for (int n = 0; n < 4; n++) o_acc[qi][n] = z4;
        ls_acc[qi] = z4;
        m[qi] = NEG_INF;
    }

    // staging lane roles (same for K and V): per call each thread loads 2 chunks of each
    const int r0_ = tid >> 3, c0_ = tid & 7;            // chunk (r0_, c0_)
    const int r1_ = (tid + 256) >> 3, c1_ = (tid + 256) & 7;

#define STAGE(buf, k0s)                                                                    \
    do {                                                                                   \
        gload16(kbase + (size_t)((k0s) + r0_) * HD + ((c0_ ^ (r0_ & 7)) * 8), &Klds[buf][tid * 8]);          \
        gload16(kbase + (size_t)((k0s) + r1_) * HD + ((c1_ ^ (r1_ & 7)) * 8), &Klds[buf][(tid + 256) * 8]);  \
        gload16(vbase + (size_t)r0_ * TT + (k0s) + ((c0_ ^ (r0_ & 7)) * 8), &Vlds[buf][tid * 8]);            \
        gload16(vbase + (size_t)r1_ * TT + (k0s) + ((c1_ ^ (r1_ & 7)) * 8), &Vlds[buf][(tid + 256) * 8]);    \
    } while (0)

    const int nkt = q0 / 64 + 2;
    STAGE(0, 0);
    for (int kt = 0; kt < nkt; ++kt) {
        const int k0 = kt * 64;
        const int cur = kt & 1;
        if (kt + 1 < nkt) {
            STAGE(cur ^ 1, k0 + 64);
            asm volatile("s_waitcnt vmcnt(4)" ::: "memory");  // tile kt's 4 loads done
        } else {
            asm volatile("s_waitcnt vmcnt(0)" ::: "memory");
        }
        __builtin_amdgcn_s_barrier();
        if (k0 <= qw0 + 31) {
            const int sw = l15 & 7;   // row&7 for K rows (kb*16+l15) and V rows (n*16+l15)
            // swapped QK^T: s2[qi][kb]: q = qi*16 + l15, key = k0 + kb*16 + g*4 + e
            f32x4 s2[2][4];
            __builtin_amdgcn_s_setprio(1);
#pragma unroll
            for (int kb = 0; kb < 4; kb++) {
                bf16x8 kf0 = *(const bf16x8*)&Klds[cur][(kb * 16 + l15) * 64 + ((g ^ sw) * 8)];
                bf16x8 kf1 = *(const bf16x8*)&Klds[cur][(kb * 16 + l15) * 64 + (((4 + g) ^ sw) * 8)];
#pragma unroll
                for (int qi = 0; qi < 2; qi++) {
                    f32x4 t0 = __builtin_amdgcn_mfma_f32_16x16x32_bf16(kf0, qf[qi][0], z4, 0, 0, 0);
                    s2[qi][kb] = __builtin_amdgcn_mfma_f32_16x16x32_bf16(kf1, qf[qi][1], t0, 0, 0, 0);
                }
            }
            __builtin_amdgcn_s_setprio(0);
            if (k0 + 63 > qw0) {
#pragma unroll
                for (int qi = 0; qi < 2; qi++)
#pragma unroll
                    for (int kb = 0; kb < 4; kb++)
#pragma unroll
                        for (int e = 0; e < 4; e++) {
                            const int kk = k0 + kb * 16 + g * 4 + e;
                            const int qq = qw0 + qi * 16 + l15;
                            if (kk > qq) s2[qi][kb][e] = NEG_INF;
                        }
            }
            // in-register online softmax, exp2 domain (q = l15 per lane)
#pragma unroll
            for (int qi = 0; qi < 2; qi++) {
                f32x4 mx = s2[qi][0];
#pragma unroll
                for (int kb = 1; kb < 4; kb++)
#pragma unroll
                    for (int e = 0; e < 4; e++) mx[e] = fmaxf(mx[e], s2[qi][kb][e]);
                float pmax = fmaxf(fmaxf(mx[0], mx[1]), fmaxf(mx[2], mx[3]));
                pmax = fmaxf(pmax, __shfl_xor(pmax, 16));
                pmax = fmaxf(pmax, __shfl_xor(pmax, 32));
                float mn = m[qi];
                const int resc = !__all(pmax <= mn + 11.541560f);   // defer-max (2^11.54 = e^8)
                if (resc) {
                    const float mold = mn;
                    mn = fmaxf(mold, pmax);
                    m[qi] = mn;
                    const float sc2 = ex2(mold - mn);
#pragma unroll
                    for (int e = 0; e < 4; e++) {
                        const float sce = __shfl(sc2, (lane & 48) + (((lane >> 4) & 3) << 2) + e);
                        ls_acc[qi][e] *= sce;
#pragma unroll
                        for (int n = 0; n < 4; n++) o_acc[qi][n][e] *= sce;
                    }
                }
                const int prow = qi * 16 + l15;
                u16* pb = &Plds[wv][prow * 64];
#pragma unroll
                for (int kb = 0; kb < 4; kb++) {
                    ushort4 pk;
                    pk.x = b16(ex2(s2[qi][kb][0] - mn));
                    pk.y = b16(ex2(s2[qi][kb][1] - mn));
                    pk.z = b16(ex2(s2[qi][kb][2] - mn));
                    pk.w = b16(ex2(s2[qi][kb][3] - mn));
                    *(ushort4*)&pb[(((kb << 2) + g) ^ l15) * 4] = pk;
                }
            }
            asm volatile("s_waitcnt lgkmcnt(0)" ::: "memory");
            // PV: A = P (row q=l15, keys g*8+j), B = V^T; ls += P x ones (MFMA row-sum)
            const int sw2 = l15 & 7;
#pragma unroll
            for (int ks = 0; ks < 2; ks++) {
                bf16x8 vf[4];
#pragma unroll
                for (int n = 0; n < 4; n++)
                    vf[n] = *(const bf16x8*)&Vlds[cur][(n * 16 + l15) * 64 + (((ks * 4 + g) ^ sw2) * 8)];
                __builtin_amdgcn_s_setprio(1);
#pragma unroll
                for (int qi = 0; qi < 2; qi++) {
                    const u16* pb = &Plds[wv][(qi * 16 + l15) * 64];
                    const int G0 = ((ks << 3) + (g << 1)) ^ l15;
                    const int G1 = ((ks << 3) + (g << 1) + 1) ^ l15;
                    const uint2 ra = *(const uint2*)&pb[G0 * 4];
                    const uint2 rb = *(const uint2*)&pb[G1 * 4];
                    union { uint32_t w[4]; bf16x8 v; } pu;
                    pu.w[0] = ra.x; pu.w[1] = ra.y; pu.w[2] = rb.x; pu.w[3] = rb.y;
#pragma unroll
                    for (int n = 0; n < 4; n++)
                        o_acc[qi][n] = __builtin_amdgcn_mfma_f32_16x16x32_bf16(pu.v, vf[n], o_acc[qi][n], 0, 0, 0);
                    ls_acc[qi] = __builtin_amdgcn_mfma_f32_16x16x32_bf16(pu.v, ones, ls_acc[qi], 0, 0, 0);
                }
                __builtin_amdgcn_s_setprio(0);
            }
        }
        __builtin_amdgcn_s_barrier();
    }
#undef STAGE

    const int b = bh >> 4, h = bh & 15;
#pragma unroll
    for (int qi = 0; qi < 2; qi++) {
#pragma unroll
        for (int e = 0; e < 4; e++) {
            const float inv = 1.f / ls_acc[qi][e];      // same layout as o_acc: no shfl
            const int t = qw0 + qi * 16 + g * 4 + e;
#pragma unroll
            for (int n = 0; n < 4; n++)
                o[((size_t)(b * TT + t)) * DD + h * HD + n * 16 + l15] = b16(o_acc[qi][n][e] * inv);
        }
    }
}

// ---------------- launch ----------------

extern "C" void kernel_launch(void* const* d_in, const int* in_sizes, int n_in,
                              void* d_out, int out_size, void* d_ws, size_t ws_size,
                              hipStream_t stream)
{
    const float* x     = (const float*)d_in[0];
    const float* w_qkv = (const float*)d_in[1];
    const float* w_o   = (const float*)d_in[2];
    float* out = (float*)d_out;
    char* ws = (char*)d_ws;

    u16* xb    = (u16*)(ws);                 // 8192x1024        16 MB
    u16* wqkvT = (u16*)(ws + 16777216);      // 3072x1024         6 MB
    u16* woT   = (u16*)(ws + 23068672);      // 1024x1024         2 MB
    u16* wsq   = (u16*)(ws + 25165824);      // [B,H,T,64]       16 MB
    u16* wsk   = (u16*)(ws + 41943040);      // [B,H,T,64]       16 MB
    u16* wsvT  = (u16*)(ws + 58720256);      // [B,H,64,T]       16 MB
    u16* attno = (u16*)(ws + 75497472);      // [B*T, D]         16 MB

    f32_to_bf16_vec<<<8192, 256, 0, stream>>>(x, xb, 2097152);
    dim3 tb(32, 8);
    transpose_f32_bf16<<<dim3(96, 32), tb, 0, stream>>>(w_qkv, wqkvT, 1024, 3072);
    transpose_f32_bf16<<<dim3(32, 32), tb, 0, stream>>>(w_o,   woT,   1024, 1024);

    gemm10<0><<<1536, 512, 0, stream>>>(xb, wqkvT, 3072, 1024, 1536, wsq, wsk, wsvT, nullptr);
    attn_fwd<<<1024, 256, 0, stream>>>(wsq, wsk, wsvT, attno);
    gemm10<1><<<512, 512, 0, stream>>>(attno, woT, 1024, 1024, 512, nullptr, nullptr, nullptr, out);
}

// Round 20
// 152.771 us; speedup vs baseline: 1.0107x; 1.0107x over previous
//
#include <hip/hip_runtime.h>
#include <hip/hip_bf16.h>
#include <stdint.h>

#define HD 64
#define NH 16
#define TT 2048
#define DD 1024

typedef uint16_t u16;
typedef __bf16 bf16_t;
typedef bf16_t bf16x8 __attribute__((ext_vector_type(8)));
typedef float f32x4 __attribute__((ext_vector_type(4)));

__device__ __forceinline__ u16 f2b(float f) {
    union { float f; uint32_t u; } v; v.f = f;
    uint32_t u = v.u;
    u += 0x7fff + ((u >> 16) & 1);   // RNE
    return (u16)(u >> 16);
}

__device__ __forceinline__ u16 b16(float f) {
    union { __bf16 h; u16 u; } c; c.h = (__bf16)f; return c.u;  // HW cvt (RNE)
}

// native v_exp_f32: D = 2^S0 (single instruction; exp2f libm is ~10 VALU ops)
__device__ __forceinline__ float ex2(float x) { return __builtin_amdgcn_exp2f(x); }

__device__ __forceinline__ void gload16(const void* g, void* l) {
    __builtin_amdgcn_global_load_lds(
        (__attribute__((address_space(1))) void*)g,
        (__attribute__((address_space(3))) void*)l, 16, 0, 0);
}

// ---------------- converts ----------------

__global__ void f32_to_bf16_vec(const float* __restrict__ in, u16* __restrict__ out, int n4) {
    int i = blockIdx.x * 256 + threadIdx.x;
    if (i >= n4) return;
    float4 v = ((const float4*)in)[i];
    ushort4 r;
    r.x = f2b(v.x); r.y = f2b(v.y); r.z = f2b(v.z); r.w = f2b(v.w);
    ((ushort4*)out)[i] = r;
}

// out[c][r] = bf16(in[r][c]); R,C multiples of 32; block (32,8)
__global__ void transpose_f32_bf16(const float* __restrict__ in, u16* __restrict__ out, int R, int C) {
    __shared__ float tile[32][33];
    const int tx = threadIdx.x, ty = threadIdx.y;
    const int c0 = blockIdx.x * 32, r0 = blockIdx.y * 32;
#pragma unroll
    for (int j = 0; j < 32; j += 8)
        tile[ty + j][tx] = in[(size_t)(r0 + ty + j) * C + c0 + tx];
    __syncthreads();
#pragma unroll
    for (int j = 0; j < 32; j += 8)
        out[(size_t)(c0 + ty + j) * R + r0 + tx] = f2b(tile[tx][ty + j]);
}

// ---------------- GEMM C = A[M,K] * Bt[N,K]^T, bf16 in, f32 acc ----------------
// gemm10: BM=128 x BN=128, BK=64, 512 thr (8 waves 4Mx2N, 32x64/wave).
// 2-slot LDS = 64 KB -> 2 blocks/CU. 16 sync chains: per K-tile {vmcnt(0) of
// loads issued a full iteration ago -> ONE barrier -> STG(t+1) -> 12 ds_read ->
// 16 MFMA}. chunk^(row&7) swizzle via pre-swizzled global src.
// XCD swizzle, B-reuse order (r18): XCD owns row panels [8k,8k+8); 8 consecutive
// blocks share one B col-panel (L2-resident) -> FETCH 49MB (near-ideal).
// r20: MODE0 q/k epilogue bounced through LDS scratch (dead As, 32KB) so global
// stores are 16B coalesced (r19 had an 8B-copy width bug; fixed with uint4).
// MODE 0: scatter epilogue -> q (x log2e/8), k, vT.  MODE 1: f32 store.

template<int MODE>
__global__ __launch_bounds__(512, 4)
void gemm10(const u16* __restrict__ A, const u16* __restrict__ Bt,
            int N, int K, int nwg,
            u16* __restrict__ oq, u16* __restrict__ ok, u16* __restrict__ ovT,
            float* __restrict__ of)
{
    __shared__ __align__(16) u16 As[2][128 * 64];   // 32 KiB
    __shared__ __align__(16) u16 Bs[2][128 * 64];   // 32 KiB
    const int tid = threadIdx.x;
    const int lane = tid & 63, l15 = lane & 15, g = lane >> 4;
    const int wid = tid >> 6, wm = wid >> 1, wn = wid & 1;

    // XCD-aware, B-reuse-ordered swizzle: rows fast within a col panel
    const int xcd = blockIdx.x & 7, j = blockIdx.x >> 3;
    const long row0 = (long)(xcd * 8 + (j & 7)) * 128;
    const long col0 = (long)(j >> 3) * 128;

    const u16* Ag = A + row0 * K;
    const u16* Bg = Bt + col0 * K;

    const f32x4 z4 = {0.f, 0.f, 0.f, 0.f};
    f32x4 acc[2][4];
#pragma unroll
    for (int i = 0; i < 2; i++)
#pragma unroll
        for (int n = 0; n < 4; n++) acc[i][n] = z4;

    const int sw = l15 & 7;   // read-side chunk XOR (row&7)

#define STG(t_, s_) do { const int ko = (t_) << 6;                                                  \
        { const int c = tid;       const int r_ = c >> 3;                                           \
          gload16(Ag + (size_t)r_ * K + ko + (((c & 7) ^ (r_ & 7)) << 3), &As[s_][c << 3]); }       \
        { const int c = tid + 512; const int r_ = c >> 3;                                           \
          gload16(Ag + (size_t)r_ * K + ko + (((c & 7) ^ (r_ & 7)) << 3), &As[s_][c << 3]); }       \
        { const int c = tid;       const int r_ = c >> 3;                                           \
          gload16(Bg + (size_t)r_ * K + ko + (((c & 7) ^ (r_ & 7)) << 3), &Bs[s_][c << 3]); }       \
        { const int c = tid + 512; const int r_ = c >> 3;                                           \
          gload16(Bg + (size_t)r_ * K + ko + (((c & 7) ^ (r_ & 7)) << 3), &Bs[s_][c << 3]); }       \
    } while (0)

    const int NT = K >> 6;   // 16
    STG(0, 0);
    for (int t = 0; t < NT; ++t) {
        const int cur = t & 1;
        asm volatile("s_waitcnt vmcnt(0)" ::: "memory");   // tile t's 4 loads (issued 1 iter ago)
        __builtin_amdgcn_s_barrier();                       // slot cur^1 now free
        if (t + 1 < NT) STG(t + 1, cur ^ 1);
#pragma unroll
        for (int ks = 0; ks < 2; ks++) {
            bf16x8 af[2], bfr[4];
            const int ce = ((ks * 4 + g) ^ sw) << 3;        // swizzled chunk offset (u16 units)
#pragma unroll
            for (int m = 0; m < 2; m++)
                af[m]  = *(const bf16x8*)&As[cur][(wm * 32 + m * 16 + l15) * 64 + ce];
#pragma unroll
            for (int n = 0; n < 4; n++)
                bfr[n] = *(const bf16x8*)&Bs[cur][(wn * 64 + n * 16 + l15) * 64 + ce];
            __builtin_amdgcn_s_setprio(1);
#pragma unroll
            for (int m = 0; m < 2; m++)
#pragma unroll
                for (int n = 0; n < 4; n++)
                    acc[m][n] = __builtin_amdgcn_mfma_f32_16x16x32_bf16(af[m], bfr[n], acc[m][n], 0, 0, 0);
            __builtin_amdgcn_s_setprio(0);
        }
    }
#undef STG

    if (MODE == 0) {
        const int which = (int)(col0 >> 10);
        const long b = row0 >> 11;
        if (which == 2) {
            // vT: packed ushort4 over contiguous t -- already coalesced
#pragma unroll
            for (int m = 0; m < 2; m++) {
                const long r = row0 + wm * 32 + m * 16 + g * 4;
                const long t = r & (TT - 1);
#pragma unroll
                for (int n = 0; n < 4; n++) {
                    const long c = col0 + wn * 64 + n * 16 + l15;
                    const int h  = (int)((c >> 6) & 15);
                    const int hd = (int)(c & 63);
                    ushort4 pk;
                    pk.x = f2b(acc[m][n][0]); pk.y = f2b(acc[m][n][1]);
                    pk.z = f2b(acc[m][n][2]); pk.w = f2b(acc[m][n][3]);
                    *(ushort4*)&ovT[((b * NH + h) * HD + hd) * TT + t] = pk;
                }
            }
        } else {
            // q/k: bounce through LDS scratch -> 16B coalesced global stores.
            // Scratch layout: [hh(2)][t(128)][hd(64)] u16 = 32 KB = all of As.
            const float scale = (which == 0) ? 0.18033688f : 1.0f;  // q: (1/8)*log2e
            u16* Cl = &As[0][0];
            __syncthreads();                 // all K-loop LDS reads complete
#pragma unroll
            for (int m = 0; m < 2; m++) {
                const int tt0 = wm * 32 + m * 16 + g * 4;
#pragma unroll
                for (int n = 0; n < 4; n++) {
                    const int c  = wn * 64 + n * 16 + l15;
                    const int hh = c >> 6, hd = c & 63;
#pragma unroll
                    for (int e = 0; e < 4; e++)
                        Cl[(hh << 13) + ((tt0 + e) << 6) + hd] = f2b(acc[m][n][e] * scale);
                }
            }
            __syncthreads();
            u16* outp = (which == 0) ? oq : ok;
            const int h0 = (int)((col0 >> 6) & 15);
#pragma unroll
            for (int jj = 0; jj < 4; jj++) {
                const int idx = (tid + jj * 512) << 3;   // u16 index of an 8-elem (16B) chunk
                const int hh  = idx >> 13;
                const int rem = idx & 8191;
                const int tt  = rem >> 6, hd = rem & 63;
                const long tglob = (row0 + tt) & (TT - 1);
                *(uint4*)&outp[((b * NH + h0 + hh) * TT + tglob) * HD + hd] =
                    *(const uint4*)&Cl[idx];             // full 16B copy (r19 bug: was 8B)
            }
        }
    } else {
#pragma unroll
        for (int m = 0; m < 2; m++) {
            const long r = row0 + wm * 32 + m * 16 + g * 4;
#pragma unroll
            for (int n = 0; n < 4; n++) {
                const long c = col0 + wn * 64 + n * 16 + l15;
#pragma unroll
                for (int e = 0; e < 4; e++)
                    of[(r + e) * (long)N + c] = acc[m][n][e];
            }
        }
    }
}

// ---------------- flash attention (r17-exact: MFMA row-sum) ----------------
// 1D grid 1024: blockIdx.x -> (qt heavy-first, bh). 256 threads (4 waves x 32 q).
// KV tiles of 64 keys, double-buffered (2-slot), counted vmcnt(4), raw s_barrier x2.
// K/V LDS XOR-swizzled (chunk ^ row&7, via pre-swizzled global src).
// QK^T SWAPPED: s = mfma(K,Q) -> q = lane&15, key = g*4+e (in-lane row).
// In-register online softmax, exp2 domain (v_exp_f32).
// ls computed as P x ones via one extra MFMA per (ks,qi) in o_acc's C/D layout.
// P repacked through per-wave LDS as 8B granules, granule ^ l15 swizzle.

__global__ __launch_bounds__(256, 3)
void attn_fwd(const u16* __restrict__ gq, const u16* __restrict__ gk,
              const u16* __restrict__ gvT, u16* __restrict__ o)
{
    __shared__ __align__(16) u16 Klds[2][64 * 64];   // [key][hd] swizzled
    __shared__ __align__(16) u16 Vlds[2][64 * 64];   // [hd][key] swizzled
    __shared__ __align__(16) u16 Plds[4][32 * 64];   // per-wave [q][16 x 8B granules]

    const int tid = threadIdx.x;
    const int wv = tid >> 6, lane = tid & 63, l15 = lane & 15, g = lane >> 4;
    const int bh = blockIdx.x & 63;
    const int qt = 15 - (blockIdx.x >> 6);       // heavy tiles dispatch first
    const int q0 = qt * 128;
    const int qw0 = q0 + wv * 32;

    const u16* qbase = gq + (size_t)bh * TT * HD;
    const u16* kbase = gk + (size_t)bh * TT * HD;
    const u16* vbase = gvT + (size_t)bh * HD * TT;

    const float NEG_INF = -__builtin_inff();
    const f32x4 z4 = {0.f, 0.f, 0.f, 0.f};
    const bf16x8 ones = {(__bf16)1.f, (__bf16)1.f, (__bf16)1.f, (__bf16)1.f,
                         (__bf16)1.f, (__bf16)1.f, (__bf16)1.f, (__bf16)1.f};

    bf16x8 qf[2][2];
#pragma unroll
    for (int qi = 0; qi < 2; qi++)
#pragma unroll
        for (int hs = 0; hs < 2; hs++)
            qf[qi][hs] = *(const bf16x8*)(qbase + (size_t)(qw0 + qi * 16 + l15) * HD + hs * 32 + g * 8);

    f32x4 o_acc[2][4];
    f32x4 ls_acc[2];            // row-sum of P, in o_acc's C/D layout (row q = g*4+e)
    float m[2];
#pragma unroll
    for (int qi = 0; qi < 2; qi++) {
#pragma unroll
        for (int n = 0; n < 4; n++) o_acc[qi][n] = z4;
        ls_acc[qi] = z4;
        m[qi] = NEG_INF;
    }

    // staging lane roles (same for K and V): per call each thread loads 2 chunks of each
    const int r0_ = tid >> 3, c0_ = tid & 7;            // chunk (r0_, c0_)
    const int r1_ = (tid + 256) >> 3, c1_ = (tid + 256) & 7;

#define STAGE(buf, k0s)                                                                    \
    do {                                                                                   \
        gload16(kbase + (size_t)((k0s) + r0_) * HD + ((c0_ ^ (r0_ & 7)) * 8), &Klds[buf][tid * 8]);          \
        gload16(kbase + (size_t)((k0s) + r1_) * HD + ((c1_ ^ (r1_ & 7)) * 8), &Klds[buf][(tid + 256) * 8]);  \
        gload16(vbase + (size_t)r0_ * TT + (k0s) + ((c0_ ^ (r0_ & 7)) * 8), &Vlds[buf][tid * 8]);            \
        gload16(vbase + (size_t)r1_ * TT + (k0s) + ((c1_ ^ (r1_ & 7)) * 8), &Vlds[buf][(tid + 256) * 8]);    \
    } while (0)

    const int nkt = q0 / 64 + 2;
    STAGE(0, 0);
    for (int kt = 0; kt < nkt; ++kt) {
        const int k0 = kt * 64;
        const int cur = kt & 1;
        if (kt + 1 < nkt) {
            STAGE(cur ^ 1, k0 + 64);
            asm volatile("s_waitcnt vmcnt(4)" ::: "memory");  // tile kt's 4 loads done
        } else {
            asm volatile("s_waitcnt vmcnt(0)" ::: "memory");
        }
        __builtin_amdgcn_s_barrier();
        if (k0 <= qw0 + 31) {
            const int sw = l15 & 7;   // row&7 for K rows (kb*16+l15) and V rows (n*16+l15)
            // swapped QK^T: s2[qi][kb]: q = qi*16 + l15, key = k0 + kb*16 + g*4 + e
            f32x4 s2[2][4];
            __builtin_amdgcn_s_setprio(1);
#pragma unroll
            for (int kb = 0; kb < 4; kb++) {
                bf16x8 kf0 = *(const bf16x8*)&Klds[cur][(kb * 16 + l15) * 64 + ((g ^ sw) * 8)];
                bf16x8 kf1 = *(const bf16x8*)&Klds[cur][(kb * 16 + l15) * 64 + (((4 + g) ^ sw) * 8)];
#pragma unroll
                for (int qi = 0; qi < 2; qi++) {
                    f32x4 t0 = __builtin_amdgcn_mfma_f32_16x16x32_bf16(kf0, qf[qi][0], z4, 0, 0, 0);
                    s2[qi][kb] = __builtin_amdgcn_mfma_f32_16x16x32_bf16(kf1, qf[qi][1], t0, 0, 0, 0);
                }
            }
            __builtin_amdgcn_s_setprio(0);
            if (k0 + 63 > qw0) {
#pragma unroll
                for (int qi = 0; qi < 2; qi++)
#pragma unroll
                    for (int kb = 0; kb < 4; kb++)
#pragma unroll
                        for (int e = 0; e < 4; e++) {
                            const int kk = k0 + kb * 16 + g * 4 + e;
                            const int qq = qw0 + qi * 16 + l15;
                            if (kk > qq) s2[qi][kb][e] = NEG_INF;
                        }
            }
            // in-register online softmax, exp2 domain (q = l15 per lane)
#pragma unroll
            for (int qi = 0; qi < 2; qi++) {
                f32x4 mx = s2[qi][0];
#pragma unroll
                for (int kb = 1; kb < 4; kb++)
#pragma unroll
                    for (int e = 0; e < 4; e++) mx[e] = fmaxf(mx[e], s2[qi][kb][e]);
                float pmax = fmaxf(fmaxf(mx[0], mx[1]), fmaxf(mx[2], mx[3]));
                pmax = fmaxf(pmax, __shfl_xor(pmax, 16));
                pmax = fmaxf(pmax, __shfl_xor(pmax, 32));
                float mn = m[qi];
                const int resc = !__all(pmax <= mn + 11.541560f);   // defer-max (2^11.54 = e^8)
                if (resc) {
                    const float mold = mn;
                    mn = fmaxf(mold, pmax);
                    m[qi] = mn;
                    const float sc2 = ex2(mold - mn);
#pragma unroll
                    for (int e = 0; e < 4; e++) {
                        const float sce = __shfl(sc2, (lane & 48) + (((lane >> 4) & 3) << 2) + e);
                        ls_acc[qi][e] *= sce;
#pragma unroll
                        for (int n = 0; n < 4; n++) o_acc[qi][n][e] *= sce;
                    }
                }
                const int prow = qi * 16 + l15;
                u16* pb = &Plds[wv][prow * 64];
#pragma unroll
                for (int kb = 0; kb < 4; kb++) {
                    ushort4 pk;
                    pk.x = b16(ex2(s2[qi][kb][0] - mn));
                    pk.y = b16(ex2(s2[qi][kb][1] - mn));
                    pk.z = b16(ex2(s2[qi][kb][2] - mn));
                    pk.w = b16(ex2(s2[qi][kb][3] - mn));
                    *(ushort4*)&pb[(((kb << 2) + g) ^ l15) * 4] = pk;
                }
            }
            asm volatile("s_waitcnt lgkmcnt(0)" ::: "memory");
            // PV: A = P (row q=l15, keys g*8+j), B = V^T; ls += P x ones (MFMA row-sum)
            const int sw2 = l15 & 7;
#pragma unroll
            for (int ks = 0; ks < 2; ks++) {
                bf16x8 vf[4];
#pragma unroll
                for (int n = 0; n < 4; n++)
                    vf[n] = *(const bf16x8*)&Vlds[cur][(n * 16 + l15) * 64 + (((ks * 4 + g) ^ sw2) * 8)];
                __builtin_amdgcn_s_setprio(1);
#pragma unroll
                for (int qi = 0; qi < 2; qi++) {
                    const u16* pb = &Plds[wv][(qi * 16 + l15) * 64];
                    const int G0 = ((ks << 3) + (g << 1)) ^ l15;
                    const int G1 = ((ks << 3) + (g << 1) + 1) ^ l15;
                    const uint2 ra = *(const uint2*)&pb[G0 * 4];
                    const uint2 rb = *(const uint2*)&pb[G1 * 4];
                    union { uint32_t w[4]; bf16x8 v; } pu;
                    pu.w[0] = ra.x; pu.w[1] = ra.y; pu.w[2] = rb.x; pu.w[3] = rb.y;
#pragma unroll
                    for (int n = 0; n < 4; n++)
                        o_acc[qi][n] = __builtin_amdgcn_mfma_f32_16x16x32_bf16(pu.v, vf[n], o_acc[qi][n], 0, 0, 0);
                    ls_acc[qi] = __builtin_amdgcn_mfma_f32_16x16x32_bf16(pu.v, ones, ls_acc[qi], 0, 0, 0);
                }
                __builtin_amdgcn_s_setprio(0);
            }
        }
        __builtin_amdgcn_s_barrier();
    }
#undef STAGE

    const int b = bh >> 4, h = bh & 15;
#pragma unroll
    for (int qi = 0; qi < 2; qi++) {
#pragma unroll
        for (int e = 0; e < 4; e++) {
            const float inv = 1.f / ls_acc[qi][e];      // same layout as o_acc: no shfl
            const int t = qw0 + qi * 16 + g * 4 + e;
#pragma unroll
            for (int n = 0; n < 4; n++)
                o[((size_t)(b * TT + t)) * DD + h * HD + n * 16 + l15] = b16(o_acc[qi][n][e] * inv);
        }
    }
}

// ---------------- launch ----------------

extern "C" void kernel_launch(void* const* d_in, const int* in_sizes, int n_in,
                              void* d_out, int out_size, void* d_ws, size_t ws_size,
                              hipStream_t stream)
{
    const float* x     = (const float*)d_in[0];
    const float* w_qkv = (const float*)d_in[1];
    const float* w_o   = (const float*)d_in[2];
    float* out = (float*)d_out;
    char* ws = (char*)d_ws;

    u16* xb    = (u16*)(ws);                 // 8192x1024        16 MB
    u16* wqkvT = (u16*)(ws + 16777216);      // 3072x1024         6 MB
    u16* woT   = (u16*)(ws + 23068672);      // 1024x1024         2 MB
    u16* wsq   = (u16*)(ws + 25165824);      // [B,H,T,64]       16 MB
    u16* wsk   = (u16*)(ws + 41943040);      // [B,H,T,64]       16 MB
    u16* wsvT  = (u16*)(ws + 58720256);      // [B,H,64,T]       16 MB
    u16* attno = (u16*)(ws + 75497472);      // [B*T, D]         16 MB

    f32_to_bf16_vec<<<8192, 256, 0, stream>>>(x, xb, 2097152);
    dim3 tb(32, 8);
    transpose_f32_bf16<<<dim3(96, 32), tb, 0, stream>>>(w_qkv, wqkvT, 1024, 3072);
    transpose_f32_bf16<<<dim3(32, 32), tb, 0, stream>>>(w_o,   woT,   1024, 1024);

    gemm10<0><<<1536, 512, 0, stream>>>(xb, wqkvT, 3072, 1024, 1536, wsq, wsk, wsvT, nullptr);
    attn_fwd<<<1024, 256, 0, stream>>>(wsq, wsk, wsvT, attno);
    gemm10<1><<<512, 512, 0, stream>>>(attno, woT, 1024, 1024, 512, nullptr, nullptr, nullptr, out);
}